// Round 9
// baseline (340.416 us; speedup 1.0000x reference)
//
#include <hip/hip_runtime.h>
#include <math.h>

#define NN 50000
#define EE 800000
#define NPAD 50176   // 196*256
#define CPAD 68

typedef __attribute__((ext_vector_type(8))) short short8v;
typedef __attribute__((ext_vector_type(4))) float f32x4;

static __device__ __forceinline__ short bf16r(float x) {
  union { float f; unsigned u; } v; v.f = x;
  unsigned r = v.u + 0x7FFFu + ((v.u >> 16) & 1u);
  return (short)(r >> 16);
}
static __device__ __forceinline__ float bf2f(unsigned u) {
  union { unsigned u; float f; } v; v.u = u << 16;
  return v.f;
}
static __device__ __forceinline__ unsigned pk2(float a, float b) {
  return (unsigned)(unsigned short)bf16r(a) | ((unsigned)(unsigned short)bf16r(b) << 16);
}

// ws layout (float offsets), total 19,254,272 floats = 77.017 MB:
//   z     @ 0           50,176
//   U     @ 50,176      3,200,000   [overlays: cur @50,176 | bsum @100,352 | M @100,608]
//   tq    @ 3,250,176   3,200,000   [overlay after edge: wscb (65,536 bf16)]
//   w2kT  @ 6,450,176   1,024
//   w2vT  @ 6,451,200   1,024
//   wlvb  @ 6,452,224   2,048
//   rec   @ 6,454,272   12,800,000  (64 B per edge)
// rec: [0]=src [1]=dst [2]=cl [3]=pad [4..7]=ea f32x4 [8..11]=hk bf16x8 [12..15]=hv bf16x8

// ---------- fold: M = (W_q@W_dot)@W_lin_k^T ; W2{k,v}->bf16 frag layout; Wlv->bf16 [o][c] ----------
__global__ __launch_bounds__(256) void fold_kernel(
    const float* __restrict__ Wq, const float* __restrict__ Wdot,
    const float* __restrict__ Wlk, const float* __restrict__ W2k,
    const float* __restrict__ W2v, const float* __restrict__ Wlv,
    float* __restrict__ M, unsigned short* __restrict__ w2kT,
    unsigned short* __restrict__ w2vT, unsigned short* __restrict__ wlvb)
{
  __shared__ float tmp[2048];
  const int tid = threadIdx.x;
#pragma unroll
  for (int r = 0; r < 8; ++r) {
    int idx = tid + r * 256;
    int cin = idx >> 5, d = idx & 31;
    float a = 0.f;
    for (int j = 0; j < 32; ++j) a = fmaf(Wq[cin * 32 + j], Wdot[j * 32 + d], a);
    tmp[idx] = a;
  }
  __syncthreads();
#pragma unroll
  for (int r = 0; r < 16; ++r) {
    int idx = tid + r * 256;
    int cin = idx >> 6, c = idx & 63;
    float a = 0.f;
    for (int d = 0; d < 32; ++d) a = fmaf(tmp[cin * 32 + d], Wlk[c * 32 + d], a);
    M[idx] = a;
  }
#pragma unroll
  for (int r = 0; r < 8; ++r) {
    int idx = tid + r * 256;
    int c = idx >> 5, k = idx & 31, h = k >> 2, a = k & 3;
    w2kT[idx] = (unsigned short)bf16r(W2k[h * 256 + c * 4 + a]);
    w2vT[idx] = (unsigned short)bf16r(W2v[h * 256 + c * 4 + a]);
  }
#pragma unroll
  for (int r = 0; r < 16; ++r) {
    int idx = tid + r * 256;
    int o = idx >> 6, c = idx & 63;
    wlvb[idx] = (unsigned short)bf16r(Wlv[c * 64 + o]);
  }
}

// ---------- Wscb[(p*64+o)*64+c] = bf16(Wsc[c*1024 + p*64 + o]) ----------
__global__ __launch_bounds__(256) void prep_wsc(
    const float* __restrict__ Wsc, unsigned short* __restrict__ wscb)
{
  int w = blockIdx.x * 256 + threadIdx.x;
  int c = w & 63, o = (w >> 6) & 63, p = w >> 12;
  wscb[w] = (unsigned short)bf16r(Wsc[c * 1024 + p * 64 + o]);
}

// ---------- counting sort (in-place in cur) ----------
__global__ __launch_bounds__(256) void hist_kernel(
    const int* __restrict__ edst, int* __restrict__ cur)
{
  int e = blockIdx.x * 256 + threadIdx.x;
  atomicAdd(&cur[edst[e]], 1);
}

__global__ __launch_bounds__(256) void scanA_kernel(
    int* __restrict__ cur, int* __restrict__ bsum)
{
  __shared__ int s[256];
  const int tid = threadIdx.x;
  const int i = blockIdx.x * 256 + tid;
  int v = cur[i];
  s[tid] = v;
  __syncthreads();
  for (int off = 1; off < 256; off <<= 1) {
    int t = (tid >= off) ? s[tid - off] : 0;
    __syncthreads();
    s[tid] += t;
    __syncthreads();
  }
  cur[i] = s[tid] - v;
  if (tid == 255) bsum[blockIdx.x] = s[255];
}

__global__ __launch_bounds__(256) void scanB_kernel(int* __restrict__ bsum)
{
  __shared__ int s[256];
  const int tid = threadIdx.x;
  int v = (tid < 196) ? bsum[tid] : 0;
  s[tid] = v;
  __syncthreads();
  for (int off = 1; off < 256; off <<= 1) {
    int t = (tid >= off) ? s[tid - off] : 0;
    __syncthreads();
    s[tid] += t;
    __syncthreads();
  }
  if (tid < 196) bsum[tid] = s[tid] - v;
}

__global__ __launch_bounds__(256) void scanC_kernel(
    int* __restrict__ cur, const int* __restrict__ bsum)
{
  const int i = blockIdx.x * 256 + threadIdx.x;
  cur[i] += bsum[blockIdx.x];
}

// ---------- fused scatter: one 64B record per edge at rank r (nontemporal stores) ----------
__global__ __launch_bounds__(256) void scatter_fused(
    const int* __restrict__ esrc, const int* __restrict__ edst,
    const float* __restrict__ ea, const float* __restrict__ eb,
    const float* __restrict__ pos, const float* __restrict__ W1k,
    const float* __restrict__ W1v, int* __restrict__ cur,
    float* __restrict__ rec)
{
  int e = blockIdx.x * 256 + threadIdx.x;
  int s = esrc[e], d = edst[e];
  int r = atomicAdd(&cur[d], 1);
  float dx = pos[d * 3 + 0] - pos[s * 3 + 0];
  float dy = pos[d * 3 + 1] - pos[s * 3 + 1];
  float dz = pos[d * 3 + 2] - pos[s * 3 + 2];
  float len = sqrtf(fmaf(dx, dx, fmaf(dy, dy, dz * dz)));
  float arg = 10.f - 2.f * len;
  float cl = (arg > 0.f) ? __expf(-1.f / arg) : 0.f;
  // radial MLP (f32)
  const f32x4* eb4 = reinterpret_cast<const f32x4*>(eb);
  f32x4 q0 = eb4[e * 4 + 0], q1 = eb4[e * 4 + 1],
        q2 = eb4[e * 4 + 2], q3 = eb4[e * 4 + 3];
  float ebv[16] = {q0.x, q0.y, q0.z, q0.w, q1.x, q1.y, q1.z, q1.w,
                   q2.x, q2.y, q2.z, q2.w, q3.x, q3.y, q3.z, q3.w};
  float h[16];
#pragma unroll
  for (int j = 0; j < 16; ++j) h[j] = 0.f;
#pragma unroll
  for (int b = 0; b < 16; ++b) {
    float x = ebv[b];
#pragma unroll
    for (int j = 0; j < 8; ++j) {
      h[j]     = fmaf(x, W1k[b * 8 + j], h[j]);
      h[8 + j] = fmaf(x, W1v[b * 8 + j], h[8 + j]);
    }
  }
#pragma unroll
  for (int j = 0; j < 16; ++j) h[j] = h[j] / (1.f + __expf(-h[j]));  // silu

  f32x4* rp4 = reinterpret_cast<f32x4*>(rec + (size_t)r * 16);
  f32x4 w0, w1, w2, w3;
  w0.x = __int_as_float(s); w0.y = __int_as_float(d); w0.z = cl; w0.w = 0.f;
  w1 = reinterpret_cast<const f32x4*>(ea)[e];
  w2.x = __uint_as_float(pk2(h[0], h[1]));
  w2.y = __uint_as_float(pk2(h[2], h[3]));
  w2.z = __uint_as_float(pk2(h[4], h[5]));
  w2.w = __uint_as_float(pk2(h[6], h[7]));
  w3.x = __uint_as_float(pk2(h[8], h[9]));
  w3.y = __uint_as_float(pk2(h[10], h[11]));
  w3.z = __uint_as_float(pk2(h[12], h[13]));
  w3.w = __uint_as_float(pk2(h[14], h[15]));
  __builtin_nontemporal_store(w0, rp4 + 0);
  __builtin_nontemporal_store(w1, rp4 + 1);
  __builtin_nontemporal_store(w2, rp4 + 2);
  __builtin_nontemporal_store(w3, rp4 + 3);
}

// ---------- tq = nf @ M ----------
__global__ __launch_bounds__(256) void tq_kernel(
    const float* __restrict__ nf, const float* __restrict__ M, float* __restrict__ tq)
{
  __shared__ float Ml[4096];
  __shared__ float nfl[64 * 68];
  const int tid = threadIdx.x;
  const int base = blockIdx.x * 64;
#pragma unroll
  for (int r = 0; r < 4; ++r) {
    int idx = tid + r * 256;
    reinterpret_cast<float4*>(Ml)[idx] = reinterpret_cast<const float4*>(M)[idx];
  }
#pragma unroll
  for (int r = 0; r < 4; ++r) {
    int idx = tid + r * 256;
    int row = idx >> 4, c4 = idx & 15;
    float4 v = make_float4(0.f, 0.f, 0.f, 0.f);
    if (base + row < NN) v = reinterpret_cast<const float4*>(nf)[(base + row) * 16 + c4];
    *reinterpret_cast<float4*>(&nfl[row * 68 + c4 * 4]) = v;
  }
  __syncthreads();
  const int to = tid & 15, tn = tid >> 4;
  float4 acc[4] = {make_float4(0,0,0,0), make_float4(0,0,0,0),
                   make_float4(0,0,0,0), make_float4(0,0,0,0)};
  for (int c = 0; c < 64; ++c) {
    float4 m = reinterpret_cast<const float4*>(Ml)[c * 16 + to];
#pragma unroll
    for (int i = 0; i < 4; ++i) {
      float x = nfl[(tn * 4 + i) * 68 + c];
      acc[i].x = fmaf(x, m.x, acc[i].x);
      acc[i].y = fmaf(x, m.y, acc[i].y);
      acc[i].z = fmaf(x, m.z, acc[i].z);
      acc[i].w = fmaf(x, m.w, acc[i].w);
    }
  }
#pragma unroll
  for (int i = 0; i < 4; ++i) {
    int n = base + tn * 4 + i;
    if (n < NN) reinterpret_cast<float4*>(tq)[n * 16 + to] = acc[i];
  }
}

// ---------- edge pass: 64 sorted edges/block, xs-only staging, tq read direct ----------
__global__ __launch_bounds__(256) void edge_kernel(
    const float* __restrict__ nf, const float* __restrict__ tq,
    const float* __restrict__ rec,
    const unsigned short* __restrict__ w2kT, const unsigned short* __restrict__ w2vT,
    float* __restrict__ z, float* __restrict__ U)
{
  __shared__ float xs[64 * CPAD];   // x_src; overwritten with msg
  __shared__ int   es[64];
  __shared__ int   ed[64];
  __shared__ float cl[64];
  __shared__ float evs[64];
  const int tid  = threadIdx.x;
  const int lane = tid & 63;
  const int lo = lane & 15, hi = lane >> 4;
  const int w = tid >> 6;
  const int sb = blockIdx.x * 64;
  const int row = 16 * w + lo;

  // B fragments (loop-invariant)
  short8v bk[4], bv[4];
#pragma unroll
  for (int t = 0; t < 4; ++t) {
    bk[t] = *reinterpret_cast<const short8v*>(&w2kT[(16 * t + lo) * 32 + hi * 8]);
    bv[t] = *reinterpret_cast<const short8v*>(&w2vT[(16 * t + lo) * 32 + hi * 8]);
  }
  // header: one thread per edge
  if (tid < 64) {
    float4 h0 = *reinterpret_cast<const float4*>(rec + (size_t)(sb + tid) * 16);
    es[tid] = __float_as_int(h0.x);
    ed[tid] = __float_as_int(h0.y);
    cl[tid] = h0.z;
  }
  // per-lane A-fragment inputs (linear region, L1/L2)
  const unsigned* ru = reinterpret_cast<const unsigned*>(rec);
  const size_t rb = (size_t)(sb + row) * 16;
  unsigned k01 = ru[rb + 8 + hi];
  unsigned v01 = ru[rb + 12 + hi];
  float4 a4 = *reinterpret_cast<const float4*>(rec + rb + 4);

  __syncthreads();  // es ready

  // stage x_src only (float4 aligned: CPAD=68 divisible by 4)
#pragma unroll
  for (int r = 0; r < 4; ++r) {
    int idx = tid + r * 256;
    int e = idx >> 4, c4 = idx & 15;
    float4 xv = reinterpret_cast<const float4*>(nf)[es[e] * 16 + c4];
    *reinterpret_cast<float4*>(&xs[e * CPAD + c4 * 4]) = xv;
  }

  // build A fragments while staging is in flight
  float hk0 = bf2f(k01 & 0xffffu), hk1 = bf2f(k01 >> 16);
  float hv0 = bf2f(v01 & 0xffffu), hv1 = bf2f(v01 >> 16);
  short8v ak, av;
  ak[0] = bf16r(hk0 * a4.x); ak[1] = bf16r(hk0 * a4.y);
  ak[2] = bf16r(hk0 * a4.z); ak[3] = bf16r(hk0 * a4.w);
  ak[4] = bf16r(hk1 * a4.x); ak[5] = bf16r(hk1 * a4.y);
  ak[6] = bf16r(hk1 * a4.z); ak[7] = bf16r(hk1 * a4.w);
  av[0] = bf16r(hv0 * a4.x); av[1] = bf16r(hv0 * a4.y);
  av[2] = bf16r(hv0 * a4.z); av[3] = bf16r(hv0 * a4.w);
  av[4] = bf16r(hv1 * a4.x); av[5] = bf16r(hv1 * a4.y);
  av[6] = bf16r(hv1 * a4.z); av[7] = bf16r(hv1 * a4.w);

  __syncthreads();  // xs ready

  f32x4 zero = {0.f, 0.f, 0.f, 0.f};
  f32x4 ack[4], acv[4];
#pragma unroll
  for (int t = 0; t < 4; ++t) {
    ack[t] = __builtin_amdgcn_mfma_f32_16x16x32_bf16(ak, bk[t], zero, 0, 0, 0);
    acv[t] = __builtin_amdgcn_mfma_f32_16x16x32_bf16(av, bv[t], zero, 0, 0, 0);
  }

  // score per C-row (edge erow+i): xs from LDS, tq direct from global (L1-hot, dst-sorted)
  const int erow = 16 * w + 4 * hi;
  float p0, p1, p2, p3;
  {
    const float* x0 = &xs[(erow + 0) * CPAD + lo];
    const float* x1 = &xs[(erow + 1) * CPAD + lo];
    const float* x2 = &xs[(erow + 2) * CPAD + lo];
    const float* x3 = &xs[(erow + 3) * CPAD + lo];
    const float* t0 = tq + (size_t)ed[erow + 0] * 64 + lo;
    const float* t1 = tq + (size_t)ed[erow + 1] * 64 + lo;
    const float* t2 = tq + (size_t)ed[erow + 2] * 64 + lo;
    const float* t3 = tq + (size_t)ed[erow + 3] * 64 + lo;
    p0 = (x0[0]*t0[0])*ack[0][0] + (x0[16]*t0[16])*ack[1][0] + (x0[32]*t0[32])*ack[2][0] + (x0[48]*t0[48])*ack[3][0];
    p1 = (x1[0]*t1[0])*ack[0][1] + (x1[16]*t1[16])*ack[1][1] + (x1[32]*t1[32])*ack[2][1] + (x1[48]*t1[48])*ack[3][1];
    p2 = (x2[0]*t2[0])*ack[0][2] + (x2[16]*t2[16])*ack[1][2] + (x2[32]*t2[32])*ack[2][2] + (x2[48]*t2[48])*ack[3][2];
    p3 = (x3[0]*t3[0])*ack[0][3] + (x3[16]*t3[16])*ack[1][3] + (x3[32]*t3[32])*ack[2][3] + (x3[48]*t3[48])*ack[3][3];
  }
#pragma unroll
  for (int off = 1; off < 16; off <<= 1) {
    p0 += __shfl_xor(p0, off);
    p1 += __shfl_xor(p1, off);
    p2 += __shfl_xor(p2, off);
    p3 += __shfl_xor(p3, off);
  }
  float ev0 = cl[erow + 0] * __expf(0.5f * p0);
  float ev1 = cl[erow + 1] * __expf(0.5f * p1);
  float ev2 = cl[erow + 2] * __expf(0.5f * p2);
  float ev3 = cl[erow + 3] * __expf(0.5f * p3);
  float se0 = sqrtf(ev0), se1 = sqrtf(ev1), se2 = sqrtf(ev2), se3 = sqrtf(ev3);
  if (lo < 4) {
    float ev = (lo == 0) ? ev0 : (lo == 1) ? ev1 : (lo == 2) ? ev2 : ev3;
    evs[erow + lo] = ev;
  }
  // msg[e][c] = se * x_src[c] * sv[c]  (overwrite own wave's xs rows; wave-internal order)
#pragma unroll
  for (int i = 0; i < 4; ++i) {
    const float se = (i == 0) ? se0 : (i == 1) ? se1 : (i == 2) ? se2 : se3;
    float* xr = &xs[(erow + i) * CPAD + lo];
#pragma unroll
    for (int t = 0; t < 4; ++t) {
      xr[16 * t] = se * xr[16 * t] * acv[t][i];
    }
  }
  // segmented reduce: wave w walks its own strip [16w,16w+16), lane = channel
  {
    const int c = lane;
    float acc = 0.f, evacc = 0.f;
    int prev = ed[16 * w];
    for (int r = 16 * w; r < 16 * w + 16; ++r) {
      int d = ed[r];
      if (d != prev) {
        unsafeAtomicAdd(&U[prev * 64 + c], acc);
        if (c == 0) unsafeAtomicAdd(&z[prev], evacc);
        acc = 0.f; evacc = 0.f; prev = d;
      }
      acc += xs[r * CPAD + c];
      if (c == 0) evacc += evs[r];
    }
    unsafeAtomicAdd(&U[prev * 64 + c], acc);
    if (c == 0) unsafeAtomicAdd(&z[prev], evacc);
  }
}

// ---------- final (MFMA): out = s*(U@Wlv) + einsum(nf,na,Wsc) ----------
__global__ __launch_bounds__(256, 4) void final_kernel(
    const float* __restrict__ nf, const float* __restrict__ na,
    const float* __restrict__ U, const float* __restrict__ z,
    const unsigned short* __restrict__ wscb, const unsigned short* __restrict__ wlvb,
    float* __restrict__ out)
{
  __shared__ float nfl[64 * 68];
  __shared__ float Ul[64 * 68];
  __shared__ float nal[64 * 17];
  __shared__ float sl[64];
  const int tid = threadIdx.x;
  const int lane = tid & 63;
  const int lo = lane & 15, hi = lane >> 4;
  const int w = tid >> 6;
  const int nb = blockIdx.x * 64;

#pragma unroll
  for (int r = 0; r < 4; ++r) {
    int idx = tid + r * 256;
    int row = idx >> 4, c4 = idx & 15;
    int n = nb + row; if (n >= NN) n = NN - 1;
    float4 v = reinterpret_cast<const float4*>(nf)[n * 16 + c4];
    *reinterpret_cast<float4*>(&nfl[row * 68 + c4 * 4]) = v;
    float4 u = reinterpret_cast<const float4*>(U)[n * 16 + c4];
    *reinterpret_cast<float4*>(&Ul[row * 68 + c4 * 4]) = u;
  }
#pragma unroll
  for (int r = 0; r < 4; ++r) {
    int idx = tid + r * 256;
    int row = idx >> 4, p = idx & 15;
    int n = nb + row; if (n >= NN) n = NN - 1;
    nal[row * 17 + p] = na[n * 16 + p];
  }
  if (tid < 64) {
    int n = nb + tid; if (n >= NN) n = NN - 1;
    float zz = z[n];
    sl[tid] = (zz > 0.f) ? 0.5f * rsqrtf(zz) : 0.f;
  }
  __syncthreads();

  const int row = 16 * w + lo;
  short8v anf[2], au[2];
#pragma unroll
  for (int kk = 0; kk < 2; ++kk) {
#pragma unroll
    for (int j = 0; j < 8; ++j) {
      anf[kk][j] = bf16r(nfl[row * 68 + 32 * kk + 8 * hi + j]);
      au[kk][j]  = bf16r(Ul[row * 68 + 32 * kk + 8 * hi + j]);
    }
  }

  f32x4 zeroA = {0.f, 0.f, 0.f, 0.f};
  f32x4 accS[4] = {zeroA, zeroA, zeroA, zeroA};
  f32x4 accU[4] = {zeroA, zeroA, zeroA, zeroA};

  // U @ Wlv
#pragma unroll
  for (int t = 0; t < 4; ++t) {
    short8v b0 = *reinterpret_cast<const short8v*>(&wlvb[(16 * t + lo) * 64 + 8 * hi]);
    short8v b1 = *reinterpret_cast<const short8v*>(&wlvb[(16 * t + lo) * 64 + 32 + 8 * hi]);
    accU[t] = __builtin_amdgcn_mfma_f32_16x16x32_bf16(au[0], b0, accU[t], 0, 0, 0);
    accU[t] = __builtin_amdgcn_mfma_f32_16x16x32_bf16(au[1], b1, accU[t], 0, 0, 0);
  }
  // sc einsum: 16 p-chunks (keep rolled: full unroll blows VGPR to 256 -> 1-2 waves/SIMD)
#pragma unroll 1
  for (int p = 0; p < 16; ++p) {
    f32x4 cp[4] = {zeroA, zeroA, zeroA, zeroA};
#pragma unroll
    for (int t = 0; t < 4; ++t) {
      const int bbase = (p * 64 + 16 * t + lo) * 64 + 8 * hi;
      short8v b0 = *reinterpret_cast<const short8v*>(&wscb[bbase]);
      short8v b1 = *reinterpret_cast<const short8v*>(&wscb[bbase + 32]);
      cp[t] = __builtin_amdgcn_mfma_f32_16x16x32_bf16(anf[0], b0, cp[t], 0, 0, 0);
      cp[t] = __builtin_amdgcn_mfma_f32_16x16x32_bf16(anf[1], b1, cp[t], 0, 0, 0);
    }
#pragma unroll
    for (int i = 0; i < 4; ++i) {
      float nav = nal[(16 * w + 4 * hi + i) * 17 + p];
#pragma unroll
      for (int t = 0; t < 4; ++t) accS[t][i] = fmaf(nav, cp[t][i], accS[t][i]);
    }
  }
  // write out
#pragma unroll
  for (int i = 0; i < 4; ++i) {
    int n = nb + 16 * w + 4 * hi + i;
    if (n < NN) {
      float s = sl[16 * w + 4 * hi + i];
#pragma unroll
      for (int t = 0; t < 4; ++t) {
        out[n * 64 + 16 * t + lo] = fmaf(s, accU[t][i], accS[t][i]);
      }
    }
  }
}

extern "C" void kernel_launch(void* const* d_in, const int* in_sizes, int n_in,
                              void* d_out, int out_size, void* d_ws, size_t ws_size,
                              hipStream_t stream) {
  const float* nf   = (const float*)d_in[0];
  const float* na   = (const float*)d_in[1];
  const float* eb   = (const float*)d_in[2];
  const float* ea   = (const float*)d_in[3];
  const float* pos  = (const float*)d_in[4];
  const int*   esrc = (const int*)d_in[5];
  const int*   edst = (const int*)d_in[6];
  const float* Wq   = (const float*)d_in[7];
  const float* W1k  = (const float*)d_in[8];
  const float* W2k  = (const float*)d_in[9];
  const float* W1v  = (const float*)d_in[10];
  const float* W2v  = (const float*)d_in[11];
  const float* Wlk  = (const float*)d_in[12];
  const float* Wlv  = (const float*)d_in[13];
  const float* Wdot = (const float*)d_in[14];
  const float* Wsc  = (const float*)d_in[15];
  float* out = (float*)d_out;

  float* wsf = (float*)d_ws;
  float* z    = wsf;                       // 50,176
  float* U    = wsf + 50176;               // 3,200,000
  int*   cur  = (int*)(wsf + 50176);       // overlay in U
  int*   bsum = (int*)(wsf + 100352);      // overlay in U
  float* M    = wsf + 100608;              // overlay in U (4,096)
  float* tq   = wsf + 3250176;             // 3,200,000
  unsigned short* wscb = (unsigned short*)(wsf + 3250176);  // overlay on tq (post-edge)
  unsigned short* w2kT = (unsigned short*)(wsf + 6450176);
  unsigned short* w2vT = (unsigned short*)(wsf + 6451200);
  unsigned short* wlvb = (unsigned short*)(wsf + 6452224);
  float* rec  = wsf + 6454272;             // 12,800,000 (64 B/edge)

  fold_kernel<<<1, 256, 0, stream>>>(Wq, Wdot, Wlk, W2k, W2v, Wlv, M, w2kT, w2vT, wlvb);
  tq_kernel<<<(NN + 63) / 64, 256, 0, stream>>>(nf, M, tq);
  hipMemsetAsync(cur, 0, (size_t)(NPAD + 256) * sizeof(int), stream);
  hist_kernel<<<EE / 256, 256, 0, stream>>>(edst, cur);
  scanA_kernel<<<NPAD / 256, 256, 0, stream>>>(cur, bsum);
  scanB_kernel<<<1, 256, 0, stream>>>(bsum);
  scanC_kernel<<<NPAD / 256, 256, 0, stream>>>(cur, bsum);
  scatter_fused<<<EE / 256, 256, 0, stream>>>(esrc, edst, ea, eb, pos, W1k, W1v, cur, rec);
  hipMemsetAsync(z, 0, (size_t)3250176 * sizeof(float), stream);  // z + U (kills cur/bsum/M)
  edge_kernel<<<EE / 64, 256, 0, stream>>>(nf, tq, rec, w2kT, w2vT, z, U);
  prep_wsc<<<256, 256, 0, stream>>>(Wsc, wscb);
  final_kernel<<<(NN + 63) / 64, 256, 0, stream>>>(nf, na, U, z, wscb, wlvb, out);
}

// Round 10
// 322.686 us; speedup vs baseline: 1.0549x; 1.0549x over previous
//
#include <hip/hip_runtime.h>
#include <math.h>

#define NN 50000
#define EE 800000
#define NPAD 50176   // 196*256
#define CPAD 68

typedef __attribute__((ext_vector_type(8))) short short8v;
typedef __attribute__((ext_vector_type(4))) float f32x4;

static __device__ __forceinline__ short bf16r(float x) {
  union { float f; unsigned u; } v; v.f = x;
  unsigned r = v.u + 0x7FFFu + ((v.u >> 16) & 1u);
  return (short)(r >> 16);
}
static __device__ __forceinline__ float bf2f(unsigned u) {
  union { unsigned u; float f; } v; v.u = u << 16;
  return v.f;
}
static __device__ __forceinline__ unsigned pk2(float a, float b) {
  return (unsigned)(unsigned short)bf16r(a) | ((unsigned)(unsigned short)bf16r(b) << 16);
}

// ws layout (float offsets), total 16,854,272 floats = 67.4 MB:
//   z     @ 0           50,176
//   U     @ 50,176      3,200,000   [overlays: cur @50,176 | bsum @100,352 | M @100,608]
//   tq    @ 3,250,176   3,200,000   [overlay after edge: wscb (65,536 bf16)]
//   w2kT  @ 6,450,176   1,024
//   w2vT  @ 6,451,200   1,024
//   wlvb  @ 6,452,224   2,048
//   rec   @ 6,454,272   9,600,000   (48 B per edge, LINEAR at e)
//   perm  @ 16,054,272  800,000     (rank r -> edge e)
// rec12: [0]=cl [1]=ea01(2xbf16) [2]=ea23 [3]=pad [4..7]=hk bf16x8 [8..11]=hv bf16x8

// ---------- fold: M = (W_q@W_dot)@W_lin_k^T ; W2{k,v}->bf16 frag layout; Wlv->bf16 [o][c] ----------
__global__ __launch_bounds__(256) void fold_kernel(
    const float* __restrict__ Wq, const float* __restrict__ Wdot,
    const float* __restrict__ Wlk, const float* __restrict__ W2k,
    const float* __restrict__ W2v, const float* __restrict__ Wlv,
    float* __restrict__ M, unsigned short* __restrict__ w2kT,
    unsigned short* __restrict__ w2vT, unsigned short* __restrict__ wlvb)
{
  __shared__ float tmp[2048];
  const int tid = threadIdx.x;
#pragma unroll
  for (int r = 0; r < 8; ++r) {
    int idx = tid + r * 256;
    int cin = idx >> 5, d = idx & 31;
    float a = 0.f;
    for (int j = 0; j < 32; ++j) a = fmaf(Wq[cin * 32 + j], Wdot[j * 32 + d], a);
    tmp[idx] = a;
  }
  __syncthreads();
#pragma unroll
  for (int r = 0; r < 16; ++r) {
    int idx = tid + r * 256;
    int cin = idx >> 6, c = idx & 63;
    float a = 0.f;
    for (int d = 0; d < 32; ++d) a = fmaf(tmp[cin * 32 + d], Wlk[c * 32 + d], a);
    M[idx] = a;
  }
#pragma unroll
  for (int r = 0; r < 8; ++r) {
    int idx = tid + r * 256;
    int c = idx >> 5, k = idx & 31, h = k >> 2, a = k & 3;
    w2kT[idx] = (unsigned short)bf16r(W2k[h * 256 + c * 4 + a]);
    w2vT[idx] = (unsigned short)bf16r(W2v[h * 256 + c * 4 + a]);
  }
#pragma unroll
  for (int r = 0; r < 16; ++r) {
    int idx = tid + r * 256;
    int o = idx >> 6, c = idx & 63;
    wlvb[idx] = (unsigned short)bf16r(Wlv[c * 64 + o]);
  }
}

// ---------- Wscb[(p*64+o)*64+c] = bf16(Wsc[c*1024 + p*64 + o]) ----------
__global__ __launch_bounds__(256) void prep_wsc(
    const float* __restrict__ Wsc, unsigned short* __restrict__ wscb)
{
  int w = blockIdx.x * 256 + threadIdx.x;
  int c = w & 63, o = (w >> 6) & 63, p = w >> 12;
  wscb[w] = (unsigned short)bf16r(Wsc[c * 1024 + p * 64 + o]);
}

// ---------- counting sort (in-place in cur) ----------
__global__ __launch_bounds__(256) void hist_kernel(
    const int* __restrict__ edst, int* __restrict__ cur)
{
  int e = blockIdx.x * 256 + threadIdx.x;
  atomicAdd(&cur[edst[e]], 1);
}

__global__ __launch_bounds__(256) void scanA_kernel(
    int* __restrict__ cur, int* __restrict__ bsum)
{
  __shared__ int s[256];
  const int tid = threadIdx.x;
  const int i = blockIdx.x * 256 + tid;
  int v = cur[i];
  s[tid] = v;
  __syncthreads();
  for (int off = 1; off < 256; off <<= 1) {
    int t = (tid >= off) ? s[tid - off] : 0;
    __syncthreads();
    s[tid] += t;
    __syncthreads();
  }
  cur[i] = s[tid] - v;
  if (tid == 255) bsum[blockIdx.x] = s[255];
}

__global__ __launch_bounds__(256) void scanB_kernel(int* __restrict__ bsum)
{
  __shared__ int s[256];
  const int tid = threadIdx.x;
  int v = (tid < 196) ? bsum[tid] : 0;
  s[tid] = v;
  __syncthreads();
  for (int off = 1; off < 256; off <<= 1) {
    int t = (tid >= off) ? s[tid - off] : 0;
    __syncthreads();
    s[tid] += t;
    __syncthreads();
  }
  if (tid < 196) bsum[tid] = s[tid] - v;
}

__global__ __launch_bounds__(256) void scanC_kernel(
    int* __restrict__ cur, const int* __restrict__ bsum)
{
  const int i = blockIdx.x * 256 + threadIdx.x;
  cur[i] += bsum[blockIdx.x];
}

// ---------- fused scatter: LINEAR 48B record at e; only perm[r]=e is scattered ----------
__global__ __launch_bounds__(256) void scatter_fused(
    const int* __restrict__ esrc, const int* __restrict__ edst,
    const float* __restrict__ ea, const float* __restrict__ eb,
    const float* __restrict__ pos, const float* __restrict__ W1k,
    const float* __restrict__ W1v, int* __restrict__ cur,
    int* __restrict__ perm, float* __restrict__ rec)
{
  int e = blockIdx.x * 256 + threadIdx.x;
  int s = esrc[e], d = edst[e];
  int r = atomicAdd(&cur[d], 1);
  perm[r] = e;
  float dx = pos[d * 3 + 0] - pos[s * 3 + 0];
  float dy = pos[d * 3 + 1] - pos[s * 3 + 1];
  float dz = pos[d * 3 + 2] - pos[s * 3 + 2];
  float len = sqrtf(fmaf(dx, dx, fmaf(dy, dy, dz * dz)));
  float arg = 10.f - 2.f * len;
  float cl = (arg > 0.f) ? __expf(-1.f / arg) : 0.f;
  // radial MLP (f32)
  const f32x4* eb4 = reinterpret_cast<const f32x4*>(eb);
  f32x4 q0 = eb4[e * 4 + 0], q1 = eb4[e * 4 + 1],
        q2 = eb4[e * 4 + 2], q3 = eb4[e * 4 + 3];
  float ebv[16] = {q0.x, q0.y, q0.z, q0.w, q1.x, q1.y, q1.z, q1.w,
                   q2.x, q2.y, q2.z, q2.w, q3.x, q3.y, q3.z, q3.w};
  float h[16];
#pragma unroll
  for (int j = 0; j < 16; ++j) h[j] = 0.f;
#pragma unroll
  for (int b = 0; b < 16; ++b) {
    float x = ebv[b];
#pragma unroll
    for (int j = 0; j < 8; ++j) {
      h[j]     = fmaf(x, W1k[b * 8 + j], h[j]);
      h[8 + j] = fmaf(x, W1v[b * 8 + j], h[8 + j]);
    }
  }
#pragma unroll
  for (int j = 0; j < 16; ++j) h[j] = h[j] / (1.f + __expf(-h[j]));  // silu

  f32x4 a4 = reinterpret_cast<const f32x4*>(ea)[e];
  f32x4* rp4 = reinterpret_cast<f32x4*>(rec + (size_t)e * 12);
  f32x4 w0, w1, w2;
  w0.x = cl;
  w0.y = __uint_as_float(pk2(a4.x, a4.y));
  w0.z = __uint_as_float(pk2(a4.z, a4.w));
  w0.w = 0.f;
  w1.x = __uint_as_float(pk2(h[0], h[1]));
  w1.y = __uint_as_float(pk2(h[2], h[3]));
  w1.z = __uint_as_float(pk2(h[4], h[5]));
  w1.w = __uint_as_float(pk2(h[6], h[7]));
  w2.x = __uint_as_float(pk2(h[8], h[9]));
  w2.y = __uint_as_float(pk2(h[10], h[11]));
  w2.z = __uint_as_float(pk2(h[12], h[13]));
  w2.w = __uint_as_float(pk2(h[14], h[15]));
  rp4[0] = w0;
  rp4[1] = w1;
  rp4[2] = w2;
}

// ---------- tq = nf @ M ----------
__global__ __launch_bounds__(256) void tq_kernel(
    const float* __restrict__ nf, const float* __restrict__ M, float* __restrict__ tq)
{
  __shared__ float Ml[4096];
  __shared__ float nfl[64 * 68];
  const int tid = threadIdx.x;
  const int base = blockIdx.x * 64;
#pragma unroll
  for (int r = 0; r < 4; ++r) {
    int idx = tid + r * 256;
    reinterpret_cast<float4*>(Ml)[idx] = reinterpret_cast<const float4*>(M)[idx];
  }
#pragma unroll
  for (int r = 0; r < 4; ++r) {
    int idx = tid + r * 256;
    int row = idx >> 4, c4 = idx & 15;
    float4 v = make_float4(0.f, 0.f, 0.f, 0.f);
    if (base + row < NN) v = reinterpret_cast<const float4*>(nf)[(base + row) * 16 + c4];
    *reinterpret_cast<float4*>(&nfl[row * 68 + c4 * 4]) = v;
  }
  __syncthreads();
  const int to = tid & 15, tn = tid >> 4;
  float4 acc[4] = {make_float4(0,0,0,0), make_float4(0,0,0,0),
                   make_float4(0,0,0,0), make_float4(0,0,0,0)};
  for (int c = 0; c < 64; ++c) {
    float4 m = reinterpret_cast<const float4*>(Ml)[c * 16 + to];
#pragma unroll
    for (int i = 0; i < 4; ++i) {
      float x = nfl[(tn * 4 + i) * 68 + c];
      acc[i].x = fmaf(x, m.x, acc[i].x);
      acc[i].y = fmaf(x, m.y, acc[i].y);
      acc[i].z = fmaf(x, m.z, acc[i].z);
      acc[i].w = fmaf(x, m.w, acc[i].w);
    }
  }
#pragma unroll
  for (int i = 0; i < 4; ++i) {
    int n = base + tn * 4 + i;
    if (n < NN) reinterpret_cast<float4*>(tq)[n * 16 + to] = acc[i];
  }
}

// ---------- edge pass: 64 sorted ranks/block via perm; rec/esrc/edst gathers (cache-warm) ----------
__global__ __launch_bounds__(256) void edge_kernel(
    const float* __restrict__ nf, const float* __restrict__ tq,
    const float* __restrict__ rec, const int* __restrict__ perm,
    const int* __restrict__ esrc, const int* __restrict__ edst,
    const unsigned short* __restrict__ w2kT, const unsigned short* __restrict__ w2vT,
    float* __restrict__ z, float* __restrict__ U)
{
  __shared__ float xs[64 * CPAD];   // x_src; overwritten with msg
  __shared__ int   es[64];
  __shared__ int   ed[64];
  __shared__ float cl[64];
  __shared__ float evs[64];
  const int tid  = threadIdx.x;
  const int lane = tid & 63;
  const int lo = lane & 15, hi = lane >> 4;
  const int w = tid >> 6;
  const int sb = blockIdx.x * 64;
  const int row = 16 * w + lo;

  // B fragments (loop-invariant)
  short8v bk[4], bv[4];
#pragma unroll
  for (int t = 0; t < 4; ++t) {
    bk[t] = *reinterpret_cast<const short8v*>(&w2kT[(16 * t + lo) * 32 + hi * 8]);
    bv[t] = *reinterpret_cast<const short8v*>(&w2vT[(16 * t + lo) * 32 + hi * 8]);
  }
  // per-lane edge id via perm (linear load)
  const int eL = perm[sb + row];
  // header: one thread per edge
  if (tid < 64) {
    int pe = perm[sb + tid];
    es[tid] = esrc[pe];
    ed[tid] = edst[pe];
    cl[tid] = rec[(size_t)pe * 12];
  }
  // per-lane A-fragment inputs (gathers from this lane's 48B record; L2/L3-warm)
  const unsigned* ru = reinterpret_cast<const unsigned*>(rec);
  const size_t rb = (size_t)eL * 12;
  unsigned ea01 = ru[rb + 1];
  unsigned ea23 = ru[rb + 2];
  unsigned k01 = ru[rb + 4 + hi];
  unsigned v01 = ru[rb + 8 + hi];

  __syncthreads();  // es ready

  // stage x_src only (float4 aligned: CPAD=68 divisible by 4)
#pragma unroll
  for (int r = 0; r < 4; ++r) {
    int idx = tid + r * 256;
    int e = idx >> 4, c4 = idx & 15;
    float4 xv = reinterpret_cast<const float4*>(nf)[es[e] * 16 + c4];
    *reinterpret_cast<float4*>(&xs[e * CPAD + c4 * 4]) = xv;
  }

  // build A fragments while staging is in flight
  float ax = bf2f(ea01 & 0xffffu), ay = bf2f(ea01 >> 16);
  float az = bf2f(ea23 & 0xffffu), aw = bf2f(ea23 >> 16);
  float hk0 = bf2f(k01 & 0xffffu), hk1 = bf2f(k01 >> 16);
  float hv0 = bf2f(v01 & 0xffffu), hv1 = bf2f(v01 >> 16);
  short8v ak, av;
  ak[0] = bf16r(hk0 * ax); ak[1] = bf16r(hk0 * ay);
  ak[2] = bf16r(hk0 * az); ak[3] = bf16r(hk0 * aw);
  ak[4] = bf16r(hk1 * ax); ak[5] = bf16r(hk1 * ay);
  ak[6] = bf16r(hk1 * az); ak[7] = bf16r(hk1 * aw);
  av[0] = bf16r(hv0 * ax); av[1] = bf16r(hv0 * ay);
  av[2] = bf16r(hv0 * az); av[3] = bf16r(hv0 * aw);
  av[4] = bf16r(hv1 * ax); av[5] = bf16r(hv1 * ay);
  av[6] = bf16r(hv1 * az); av[7] = bf16r(hv1 * aw);

  __syncthreads();  // xs ready

  f32x4 zero = {0.f, 0.f, 0.f, 0.f};
  f32x4 ack[4], acv[4];
#pragma unroll
  for (int t = 0; t < 4; ++t) {
    ack[t] = __builtin_amdgcn_mfma_f32_16x16x32_bf16(ak, bk[t], zero, 0, 0, 0);
    acv[t] = __builtin_amdgcn_mfma_f32_16x16x32_bf16(av, bv[t], zero, 0, 0, 0);
  }

  // score per C-row (edge erow+i): xs from LDS, tq direct from global (L1-hot, dst-sorted)
  const int erow = 16 * w + 4 * hi;
  float p0, p1, p2, p3;
  {
    const float* x0 = &xs[(erow + 0) * CPAD + lo];
    const float* x1 = &xs[(erow + 1) * CPAD + lo];
    const float* x2 = &xs[(erow + 2) * CPAD + lo];
    const float* x3 = &xs[(erow + 3) * CPAD + lo];
    const float* t0 = tq + (size_t)ed[erow + 0] * 64 + lo;
    const float* t1 = tq + (size_t)ed[erow + 1] * 64 + lo;
    const float* t2 = tq + (size_t)ed[erow + 2] * 64 + lo;
    const float* t3 = tq + (size_t)ed[erow + 3] * 64 + lo;
    p0 = (x0[0]*t0[0])*ack[0][0] + (x0[16]*t0[16])*ack[1][0] + (x0[32]*t0[32])*ack[2][0] + (x0[48]*t0[48])*ack[3][0];
    p1 = (x1[0]*t1[0])*ack[0][1] + (x1[16]*t1[16])*ack[1][1] + (x1[32]*t1[32])*ack[2][1] + (x1[48]*t1[48])*ack[3][1];
    p2 = (x2[0]*t2[0])*ack[0][2] + (x2[16]*t2[16])*ack[1][2] + (x2[32]*t2[32])*ack[2][2] + (x2[48]*t2[48])*ack[3][2];
    p3 = (x3[0]*t3[0])*ack[0][3] + (x3[16]*t3[16])*ack[1][3] + (x3[32]*t3[32])*ack[2][3] + (x3[48]*t3[48])*ack[3][3];
  }
#pragma unroll
  for (int off = 1; off < 16; off <<= 1) {
    p0 += __shfl_xor(p0, off);
    p1 += __shfl_xor(p1, off);
    p2 += __shfl_xor(p2, off);
    p3 += __shfl_xor(p3, off);
  }
  float ev0 = cl[erow + 0] * __expf(0.5f * p0);
  float ev1 = cl[erow + 1] * __expf(0.5f * p1);
  float ev2 = cl[erow + 2] * __expf(0.5f * p2);
  float ev3 = cl[erow + 3] * __expf(0.5f * p3);
  float se0 = sqrtf(ev0), se1 = sqrtf(ev1), se2 = sqrtf(ev2), se3 = sqrtf(ev3);
  if (lo < 4) {
    float ev = (lo == 0) ? ev0 : (lo == 1) ? ev1 : (lo == 2) ? ev2 : ev3;
    evs[erow + lo] = ev;
  }
  // msg[e][c] = se * x_src[c] * sv[c]  (overwrite own wave's xs rows; wave-internal order)
#pragma unroll
  for (int i = 0; i < 4; ++i) {
    const float se = (i == 0) ? se0 : (i == 1) ? se1 : (i == 2) ? se2 : se3;
    float* xr = &xs[(erow + i) * CPAD + lo];
#pragma unroll
    for (int t = 0; t < 4; ++t) {
      xr[16 * t] = se * xr[16 * t] * acv[t][i];
    }
  }
  // segmented reduce: wave w walks its own strip [16w,16w+16), lane = channel
  {
    const int c = lane;
    float acc = 0.f, evacc = 0.f;
    int prev = ed[16 * w];
    for (int r = 16 * w; r < 16 * w + 16; ++r) {
      int d = ed[r];
      if (d != prev) {
        unsafeAtomicAdd(&U[prev * 64 + c], acc);
        if (c == 0) unsafeAtomicAdd(&z[prev], evacc);
        acc = 0.f; evacc = 0.f; prev = d;
      }
      acc += xs[r * CPAD + c];
      if (c == 0) evacc += evs[r];
    }
    unsafeAtomicAdd(&U[prev * 64 + c], acc);
    if (c == 0) unsafeAtomicAdd(&z[prev], evacc);
  }
}

// ---------- final (MFMA): out = s*(U@Wlv) + einsum(nf,na,Wsc) ----------
__global__ __launch_bounds__(256, 4) void final_kernel(
    const float* __restrict__ nf, const float* __restrict__ na,
    const float* __restrict__ U, const float* __restrict__ z,
    const unsigned short* __restrict__ wscb, const unsigned short* __restrict__ wlvb,
    float* __restrict__ out)
{
  __shared__ float nfl[64 * 68];
  __shared__ float Ul[64 * 68];
  __shared__ float nal[64 * 17];
  __shared__ float sl[64];
  const int tid = threadIdx.x;
  const int lane = tid & 63;
  const int lo = lane & 15, hi = lane >> 4;
  const int w = tid >> 6;
  const int nb = blockIdx.x * 64;

#pragma unroll
  for (int r = 0; r < 4; ++r) {
    int idx = tid + r * 256;
    int row = idx >> 4, c4 = idx & 15;
    int n = nb + row; if (n >= NN) n = NN - 1;
    float4 v = reinterpret_cast<const float4*>(nf)[n * 16 + c4];
    *reinterpret_cast<float4*>(&nfl[row * 68 + c4 * 4]) = v;
    float4 u = reinterpret_cast<const float4*>(U)[n * 16 + c4];
    *reinterpret_cast<float4*>(&Ul[row * 68 + c4 * 4]) = u;
  }
#pragma unroll
  for (int r = 0; r < 4; ++r) {
    int idx = tid + r * 256;
    int row = idx >> 4, p = idx & 15;
    int n = nb + row; if (n >= NN) n = NN - 1;
    nal[row * 17 + p] = na[n * 16 + p];
  }
  if (tid < 64) {
    int n = nb + tid; if (n >= NN) n = NN - 1;
    float zz = z[n];
    sl[tid] = (zz > 0.f) ? 0.5f * rsqrtf(zz) : 0.f;
  }
  __syncthreads();

  const int row = 16 * w + lo;
  short8v anf[2], au[2];
#pragma unroll
  for (int kk = 0; kk < 2; ++kk) {
#pragma unroll
    for (int j = 0; j < 8; ++j) {
      anf[kk][j] = bf16r(nfl[row * 68 + 32 * kk + 8 * hi + j]);
      au[kk][j]  = bf16r(Ul[row * 68 + 32 * kk + 8 * hi + j]);
    }
  }

  f32x4 zeroA = {0.f, 0.f, 0.f, 0.f};
  f32x4 accS[4] = {zeroA, zeroA, zeroA, zeroA};
  f32x4 accU[4] = {zeroA, zeroA, zeroA, zeroA};

  // U @ Wlv
#pragma unroll
  for (int t = 0; t < 4; ++t) {
    short8v b0 = *reinterpret_cast<const short8v*>(&wlvb[(16 * t + lo) * 64 + 8 * hi]);
    short8v b1 = *reinterpret_cast<const short8v*>(&wlvb[(16 * t + lo) * 64 + 32 + 8 * hi]);
    accU[t] = __builtin_amdgcn_mfma_f32_16x16x32_bf16(au[0], b0, accU[t], 0, 0, 0);
    accU[t] = __builtin_amdgcn_mfma_f32_16x16x32_bf16(au[1], b1, accU[t], 0, 0, 0);
  }
  // sc einsum: 16 p-chunks (keep rolled: full unroll blows VGPR to 256 -> 1-2 waves/SIMD)
#pragma unroll 1
  for (int p = 0; p < 16; ++p) {
    f32x4 cp[4] = {zeroA, zeroA, zeroA, zeroA};
#pragma unroll
    for (int t = 0; t < 4; ++t) {
      const int bbase = (p * 64 + 16 * t + lo) * 64 + 8 * hi;
      short8v b0 = *reinterpret_cast<const short8v*>(&wscb[bbase]);
      short8v b1 = *reinterpret_cast<const short8v*>(&wscb[bbase + 32]);
      cp[t] = __builtin_amdgcn_mfma_f32_16x16x32_bf16(anf[0], b0, cp[t], 0, 0, 0);
      cp[t] = __builtin_amdgcn_mfma_f32_16x16x32_bf16(anf[1], b1, cp[t], 0, 0, 0);
    }
#pragma unroll
    for (int i = 0; i < 4; ++i) {
      float nav = nal[(16 * w + 4 * hi + i) * 17 + p];
#pragma unroll
      for (int t = 0; t < 4; ++t) accS[t][i] = fmaf(nav, cp[t][i], accS[t][i]);
    }
  }
  // write out
#pragma unroll
  for (int i = 0; i < 4; ++i) {
    int n = nb + 16 * w + 4 * hi + i;
    if (n < NN) {
      float s = sl[16 * w + 4 * hi + i];
#pragma unroll
      for (int t = 0; t < 4; ++t) {
        out[n * 64 + 16 * t + lo] = fmaf(s, accU[t][i], accS[t][i]);
      }
    }
  }
}

extern "C" void kernel_launch(void* const* d_in, const int* in_sizes, int n_in,
                              void* d_out, int out_size, void* d_ws, size_t ws_size,
                              hipStream_t stream) {
  const float* nf   = (const float*)d_in[0];
  const float* na   = (const float*)d_in[1];
  const float* eb   = (const float*)d_in[2];
  const float* ea   = (const float*)d_in[3];
  const float* pos  = (const float*)d_in[4];
  const int*   esrc = (const int*)d_in[5];
  const int*   edst = (const int*)d_in[6];
  const float* Wq   = (const float*)d_in[7];
  const float* W1k  = (const float*)d_in[8];
  const float* W2k  = (const float*)d_in[9];
  const float* W1v  = (const float*)d_in[10];
  const float* W2v  = (const float*)d_in[11];
  const float* Wlk  = (const float*)d_in[12];
  const float* Wlv  = (const float*)d_in[13];
  const float* Wdot = (const float*)d_in[14];
  const float* Wsc  = (const float*)d_in[15];
  float* out = (float*)d_out;

  float* wsf = (float*)d_ws;
  float* z    = wsf;                       // 50,176
  float* U    = wsf + 50176;               // 3,200,000
  int*   cur  = (int*)(wsf + 50176);       // overlay in U
  int*   bsum = (int*)(wsf + 100352);      // overlay in U
  float* M    = wsf + 100608;              // overlay in U (4,096)
  float* tq   = wsf + 3250176;             // 3,200,000
  unsigned short* wscb = (unsigned short*)(wsf + 3250176);  // overlay on tq (post-edge)
  unsigned short* w2kT = (unsigned short*)(wsf + 6450176);
  unsigned short* w2vT = (unsigned short*)(wsf + 6451200);
  unsigned short* wlvb = (unsigned short*)(wsf + 6452224);
  float* rec  = wsf + 6454272;             // 9,600,000 (48 B/edge, linear)
  int*   perm = (int*)(wsf + 16054272);    // 800,000

  fold_kernel<<<1, 256, 0, stream>>>(Wq, Wdot, Wlk, W2k, W2v, Wlv, M, w2kT, w2vT, wlvb);
  tq_kernel<<<(NN + 63) / 64, 256, 0, stream>>>(nf, M, tq);
  hipMemsetAsync(cur, 0, (size_t)(NPAD + 256) * sizeof(int), stream);
  hist_kernel<<<EE / 256, 256, 0, stream>>>(edst, cur);
  scanA_kernel<<<NPAD / 256, 256, 0, stream>>>(cur, bsum);
  scanB_kernel<<<1, 256, 0, stream>>>(bsum);
  scanC_kernel<<<NPAD / 256, 256, 0, stream>>>(cur, bsum);
  scatter_fused<<<EE / 256, 256, 0, stream>>>(esrc, edst, ea, eb, pos, W1k, W1v,
                                              cur, perm, rec);
  hipMemsetAsync(z, 0, (size_t)3250176 * sizeof(float), stream);  // z + U (kills cur/bsum/M)
  edge_kernel<<<EE / 64, 256, 0, stream>>>(nf, tq, rec, perm, esrc, edst,
                                           w2kT, w2vT, z, U);
  prep_wsc<<<256, 256, 0, stream>>>(Wsc, wscb);
  final_kernel<<<(NN + 63) / 64, 256, 0, stream>>>(nf, na, U, z, wscb, wlvb, out);
}

// Round 11
// 303.571 us; speedup vs baseline: 1.1214x; 1.0630x over previous
//
#include <hip/hip_runtime.h>
#include <math.h>

#define NN 50000
#define EE 800000
#define NPAD 50176   // 196*256

typedef __attribute__((ext_vector_type(8))) short short8v;
typedef __attribute__((ext_vector_type(4))) float f32x4;

static __device__ __forceinline__ short bf16r(float x) {
  union { float f; unsigned u; } v; v.f = x;
  unsigned r = v.u + 0x7FFFu + ((v.u >> 16) & 1u);
  return (short)(r >> 16);
}
static __device__ __forceinline__ float bf2f(unsigned u) {
  union { unsigned u; float f; } v; v.u = u << 16;
  return v.f;
}
static __device__ __forceinline__ unsigned pk2(float a, float b) {
  return (unsigned)(unsigned short)bf16r(a) | ((unsigned)(unsigned short)bf16r(b) << 16);
}

// ws layout (float offsets), total 16,941,568 floats = 67.8 MB:
//   z     @ 0           50,176
//   U     @ 50,176      3,200,000
//   tq    @ 3,250,176   3,200,000
//   w2kT  @ 6,450,176   1,024
//   w2vT  @ 6,451,200   1,024
//   wlvb  @ 6,452,224   2,048
//   wscb  @ 6,454,272   32,768
//   cur   @ 6,487,040   50,176 (int)
//   bsum  @ 6,537,216   256 (int)
//   M     @ 6,537,472   4,096
//   rec   @ 6,541,568   9,600,000  (48 B/edge, LINEAR at e)
//   perm  @ 16,141,568  800,000
// rec12: [0]=cl [1]=ea01 [2]=ea23 [3]=pad [4..7]=hk bf16x8 [8..11]=hv bf16x8
// dispatches (8): prep -> tq -> hist_zero -> scanA -> scanB -> scatter -> edge -> final

// ---------- prep: b0 = fold; b1..196 zero cur; b197..452 = wscb transform ----------
__global__ __launch_bounds__(256) void prep_kernel(
    const float* __restrict__ Wq, const float* __restrict__ Wdot,
    const float* __restrict__ Wlk, const float* __restrict__ W2k,
    const float* __restrict__ W2v, const float* __restrict__ Wlv,
    const float* __restrict__ Wsc, float* __restrict__ M,
    unsigned short* __restrict__ w2kT, unsigned short* __restrict__ w2vT,
    unsigned short* __restrict__ wlvb, unsigned short* __restrict__ wscb,
    int* __restrict__ cur)
{
  const int tid = threadIdx.x;
  const int b = blockIdx.x;
  if (b == 0) {
    __shared__ float tmp[2048];
#pragma unroll
    for (int r = 0; r < 8; ++r) {
      int idx = tid + r * 256;
      int cin = idx >> 5, d = idx & 31;
      float a = 0.f;
      for (int j = 0; j < 32; ++j) a = fmaf(Wq[cin * 32 + j], Wdot[j * 32 + d], a);
      tmp[idx] = a;
    }
    __syncthreads();
#pragma unroll
    for (int r = 0; r < 16; ++r) {
      int idx = tid + r * 256;
      int cin = idx >> 6, c = idx & 63;
      float a = 0.f;
      for (int d = 0; d < 32; ++d) a = fmaf(tmp[cin * 32 + d], Wlk[c * 32 + d], a);
      M[idx] = a;
    }
#pragma unroll
    for (int r = 0; r < 8; ++r) {
      int idx = tid + r * 256;
      int c = idx >> 5, k = idx & 31, h = k >> 2, a = k & 3;
      w2kT[idx] = (unsigned short)bf16r(W2k[h * 256 + c * 4 + a]);
      w2vT[idx] = (unsigned short)bf16r(W2v[h * 256 + c * 4 + a]);
    }
#pragma unroll
    for (int r = 0; r < 16; ++r) {
      int idx = tid + r * 256;
      int o = idx >> 6, c = idx & 63;
      wlvb[idx] = (unsigned short)bf16r(Wlv[c * 64 + o]);
    }
  } else if (b <= 196) {
    cur[(b - 1) * 256 + tid] = 0;
  } else {
    int w = (b - 197) * 256 + tid;
    int c = w & 63, o = (w >> 6) & 63, p = w >> 12;
    wscb[w] = (unsigned short)bf16r(Wsc[c * 1024 + p * 64 + o]);
  }
}

// ---------- hist + zero(z,U) fused ----------
__global__ __launch_bounds__(256) void hist_zero(
    const int* __restrict__ edst, int* __restrict__ cur, float4* __restrict__ zu)
{
  int i = blockIdx.x * 256 + threadIdx.x;
  float4 zf = make_float4(0.f, 0.f, 0.f, 0.f);
  zu[i] = zf;                                 // 800,000 of 812,544
  if (i < 12544) zu[800000 + i] = zf;         // remainder
  atomicAdd(&cur[edst[i]], 1);
}

__global__ __launch_bounds__(256) void scanA_kernel(
    int* __restrict__ cur, int* __restrict__ bsum)
{
  __shared__ int s[256];
  const int tid = threadIdx.x;
  const int i = blockIdx.x * 256 + tid;
  int v = cur[i];
  s[tid] = v;
  __syncthreads();
  for (int off = 1; off < 256; off <<= 1) {
    int t = (tid >= off) ? s[tid - off] : 0;
    __syncthreads();
    s[tid] += t;
    __syncthreads();
  }
  cur[i] = s[tid] - v;
  if (tid == 255) bsum[blockIdx.x] = s[255];
}

__global__ __launch_bounds__(256) void scanB_kernel(int* __restrict__ bsum)
{
  __shared__ int s[256];
  const int tid = threadIdx.x;
  int v = (tid < 196) ? bsum[tid] : 0;
  s[tid] = v;
  __syncthreads();
  for (int off = 1; off < 256; off <<= 1) {
    int t = (tid >= off) ? s[tid - off] : 0;
    __syncthreads();
    s[tid] += t;
    __syncthreads();
  }
  if (tid < 196) bsum[tid] = s[tid] - v;
}

// ---------- scatter: LINEAR 48B record at e; perm[r]=e; r folds in bsum (scanC gone) ----------
__global__ __launch_bounds__(256) void scatter_fused(
    const int* __restrict__ esrc, const int* __restrict__ edst,
    const float* __restrict__ ea, const float* __restrict__ eb,
    const float* __restrict__ pos, const float* __restrict__ W1k,
    const float* __restrict__ W1v, int* __restrict__ cur,
    const int* __restrict__ bsum, int* __restrict__ perm,
    float* __restrict__ rec)
{
  int e = blockIdx.x * 256 + threadIdx.x;
  int s = esrc[e], d = edst[e];
  int r = atomicAdd(&cur[d], 1) + bsum[d >> 8];
  perm[r] = e;
  float dx = pos[d * 3 + 0] - pos[s * 3 + 0];
  float dy = pos[d * 3 + 1] - pos[s * 3 + 1];
  float dz = pos[d * 3 + 2] - pos[s * 3 + 2];
  float len = sqrtf(fmaf(dx, dx, fmaf(dy, dy, dz * dz)));
  float arg = 10.f - 2.f * len;
  float cl = (arg > 0.f) ? __expf(-1.f / arg) : 0.f;
  const f32x4* eb4 = reinterpret_cast<const f32x4*>(eb);
  f32x4 q0 = eb4[e * 4 + 0], q1 = eb4[e * 4 + 1],
        q2 = eb4[e * 4 + 2], q3 = eb4[e * 4 + 3];
  float ebv[16] = {q0.x, q0.y, q0.z, q0.w, q1.x, q1.y, q1.z, q1.w,
                   q2.x, q2.y, q2.z, q2.w, q3.x, q3.y, q3.z, q3.w};
  float h[16];
#pragma unroll
  for (int j = 0; j < 16; ++j) h[j] = 0.f;
#pragma unroll
  for (int b = 0; b < 16; ++b) {
    float x = ebv[b];
#pragma unroll
    for (int j = 0; j < 8; ++j) {
      h[j]     = fmaf(x, W1k[b * 8 + j], h[j]);
      h[8 + j] = fmaf(x, W1v[b * 8 + j], h[8 + j]);
    }
  }
#pragma unroll
  for (int j = 0; j < 16; ++j) h[j] = h[j] / (1.f + __expf(-h[j]));  // silu

  f32x4 a4 = reinterpret_cast<const f32x4*>(ea)[e];
  f32x4* rp4 = reinterpret_cast<f32x4*>(rec + (size_t)e * 12);
  f32x4 w0, w1, w2;
  w0.x = cl;
  w0.y = __uint_as_float(pk2(a4.x, a4.y));
  w0.z = __uint_as_float(pk2(a4.z, a4.w));
  w0.w = 0.f;
  w1.x = __uint_as_float(pk2(h[0], h[1]));
  w1.y = __uint_as_float(pk2(h[2], h[3]));
  w1.z = __uint_as_float(pk2(h[4], h[5]));
  w1.w = __uint_as_float(pk2(h[6], h[7]));
  w2.x = __uint_as_float(pk2(h[8], h[9]));
  w2.y = __uint_as_float(pk2(h[10], h[11]));
  w2.z = __uint_as_float(pk2(h[12], h[13]));
  w2.w = __uint_as_float(pk2(h[14], h[15]));
  rp4[0] = w0;
  rp4[1] = w1;
  rp4[2] = w2;
}

// ---------- tq = nf @ M ----------
__global__ __launch_bounds__(256) void tq_kernel(
    const float* __restrict__ nf, const float* __restrict__ M, float* __restrict__ tq)
{
  __shared__ float Ml[4096];
  __shared__ float nfl[64 * 68];
  const int tid = threadIdx.x;
  const int base = blockIdx.x * 64;
#pragma unroll
  for (int r = 0; r < 4; ++r) {
    int idx = tid + r * 256;
    reinterpret_cast<float4*>(Ml)[idx] = reinterpret_cast<const float4*>(M)[idx];
  }
#pragma unroll
  for (int r = 0; r < 4; ++r) {
    int idx = tid + r * 256;
    int row = idx >> 4, c4 = idx & 15;
    float4 v = make_float4(0.f, 0.f, 0.f, 0.f);
    if (base + row < NN) v = reinterpret_cast<const float4*>(nf)[(base + row) * 16 + c4];
    *reinterpret_cast<float4*>(&nfl[row * 68 + c4 * 4]) = v;
  }
  __syncthreads();
  const int to = tid & 15, tn = tid >> 4;
  float4 acc[4] = {make_float4(0,0,0,0), make_float4(0,0,0,0),
                   make_float4(0,0,0,0), make_float4(0,0,0,0)};
  for (int c = 0; c < 64; ++c) {
    float4 m = reinterpret_cast<const float4*>(Ml)[c * 16 + to];
#pragma unroll
    for (int i = 0; i < 4; ++i) {
      float x = nfl[(tn * 4 + i) * 68 + c];
      acc[i].x = fmaf(x, m.x, acc[i].x);
      acc[i].y = fmaf(x, m.y, acc[i].y);
      acc[i].z = fmaf(x, m.z, acc[i].z);
      acc[i].w = fmaf(x, m.w, acc[i].w);
    }
  }
#pragma unroll
  for (int i = 0; i < 4; ++i) {
    int n = base + tn * 4 + i;
    if (n < NN) reinterpret_cast<float4*>(tq)[n * 16 + to] = acc[i];
  }
}

// ---------- edge pass: 4 INDEPENDENT waves/block, 16 ranks each, NO block barriers ----------
__global__ __launch_bounds__(256) void edge_kernel(
    const float* __restrict__ nf, const float* __restrict__ tq,
    const float* __restrict__ rec, const int* __restrict__ perm,
    const int* __restrict__ esrc, const int* __restrict__ edst,
    const unsigned short* __restrict__ w2kT, const unsigned short* __restrict__ w2vT,
    float* __restrict__ z, float* __restrict__ U)
{
  __shared__ float xsAll[4][16 * 68];
  __shared__ int   esAll[4][16];
  __shared__ int   edAll[4][16];
  __shared__ float clAll[4][16];
  __shared__ float evAll[4][16];
  const int tid  = threadIdx.x;
  const int lane = tid & 63;
  const int w = tid >> 6;
  const int lo = lane & 15, hi = lane >> 4;
  const int sb = (blockIdx.x * 4 + w) * 16;   // this wave's 16 ranks
  float* xs = xsAll[w];
  int*   es = esAll[w];
  int*   ed = edAll[w];
  float* cl = clAll[w];
  float* evs = evAll[w];

  // B fragments (loop-invariant)
  short8v bk[4], bv[4];
#pragma unroll
  for (int t = 0; t < 4; ++t) {
    bk[t] = *reinterpret_cast<const short8v*>(&w2kT[(16 * t + lo) * 32 + hi * 8]);
    bv[t] = *reinterpret_cast<const short8v*>(&w2vT[(16 * t + lo) * 32 + hi * 8]);
  }

  // record gathers issued first (A-row of this lane = lo)
  const int eL = perm[sb + lo];
  const unsigned* ru = reinterpret_cast<const unsigned*>(rec);
  const size_t rb = (size_t)eL * 12;
  unsigned ea01 = ru[rb + 1];
  unsigned ea23 = ru[rb + 2];
  unsigned k01  = ru[rb + 4 + hi];
  unsigned v01  = ru[rb + 8 + hi];

  // headers: hi==0 lanes own edge lo (same-wave LDS ordering; no block barrier)
  if (hi == 0) {
    es[lo] = esrc[eL];
    ed[lo] = edst[eL];
    cl[lo] = rec[rb];
  }
  __builtin_amdgcn_wave_barrier();

  // stage x_src rows (wave-private 16x68)
#pragma unroll
  for (int r = 0; r < 4; ++r) {
    int idx = lane + r * 64;
    int e = idx >> 4, c4 = idx & 15;
    float4 xv = reinterpret_cast<const float4*>(nf)[es[e] * 16 + c4];
    *reinterpret_cast<float4*>(&xs[e * 68 + c4 * 4]) = xv;
  }

  // build A fragments while staging is in flight
  float ax = bf2f(ea01 & 0xffffu), ay = bf2f(ea01 >> 16);
  float az = bf2f(ea23 & 0xffffu), aw = bf2f(ea23 >> 16);
  float hk0 = bf2f(k01 & 0xffffu), hk1 = bf2f(k01 >> 16);
  float hv0 = bf2f(v01 & 0xffffu), hv1 = bf2f(v01 >> 16);
  short8v ak, av;
  ak[0] = bf16r(hk0 * ax); ak[1] = bf16r(hk0 * ay);
  ak[2] = bf16r(hk0 * az); ak[3] = bf16r(hk0 * aw);
  ak[4] = bf16r(hk1 * ax); ak[5] = bf16r(hk1 * ay);
  ak[6] = bf16r(hk1 * az); ak[7] = bf16r(hk1 * aw);
  av[0] = bf16r(hv0 * ax); av[1] = bf16r(hv0 * ay);
  av[2] = bf16r(hv0 * az); av[3] = bf16r(hv0 * aw);
  av[4] = bf16r(hv1 * ax); av[5] = bf16r(hv1 * ay);
  av[6] = bf16r(hv1 * az); av[7] = bf16r(hv1 * aw);
  __builtin_amdgcn_wave_barrier();

  f32x4 zero = {0.f, 0.f, 0.f, 0.f};
  f32x4 ack[4], acv[4];
#pragma unroll
  for (int t = 0; t < 4; ++t) {
    ack[t] = __builtin_amdgcn_mfma_f32_16x16x32_bf16(ak, bk[t], zero, 0, 0, 0);
    acv[t] = __builtin_amdgcn_mfma_f32_16x16x32_bf16(av, bv[t], zero, 0, 0, 0);
  }

  // score per C-row (local rows 4hi..4hi+3)
  const int erow = 4 * hi;
  float p0, p1, p2, p3;
  {
    const float* x0 = &xs[(erow + 0) * 68 + lo];
    const float* x1 = &xs[(erow + 1) * 68 + lo];
    const float* x2 = &xs[(erow + 2) * 68 + lo];
    const float* x3 = &xs[(erow + 3) * 68 + lo];
    const float* t0 = tq + (size_t)ed[erow + 0] * 64 + lo;
    const float* t1 = tq + (size_t)ed[erow + 1] * 64 + lo;
    const float* t2 = tq + (size_t)ed[erow + 2] * 64 + lo;
    const float* t3 = tq + (size_t)ed[erow + 3] * 64 + lo;
    p0 = (x0[0]*t0[0])*ack[0][0] + (x0[16]*t0[16])*ack[1][0] + (x0[32]*t0[32])*ack[2][0] + (x0[48]*t0[48])*ack[3][0];
    p1 = (x1[0]*t1[0])*ack[0][1] + (x1[16]*t1[16])*ack[1][1] + (x1[32]*t1[32])*ack[2][1] + (x1[48]*t1[48])*ack[3][1];
    p2 = (x2[0]*t2[0])*ack[0][2] + (x2[16]*t2[16])*ack[1][2] + (x2[32]*t2[32])*ack[2][2] + (x2[48]*t2[48])*ack[3][2];
    p3 = (x3[0]*t3[0])*ack[0][3] + (x3[16]*t3[16])*ack[1][3] + (x3[32]*t3[32])*ack[2][3] + (x3[48]*t3[48])*ack[3][3];
  }
#pragma unroll
  for (int off = 1; off < 16; off <<= 1) {
    p0 += __shfl_xor(p0, off);
    p1 += __shfl_xor(p1, off);
    p2 += __shfl_xor(p2, off);
    p3 += __shfl_xor(p3, off);
  }
  float ev0 = cl[erow + 0] * __expf(0.5f * p0);
  float ev1 = cl[erow + 1] * __expf(0.5f * p1);
  float ev2 = cl[erow + 2] * __expf(0.5f * p2);
  float ev3 = cl[erow + 3] * __expf(0.5f * p3);
  float se0 = sqrtf(ev0), se1 = sqrtf(ev1), se2 = sqrtf(ev2), se3 = sqrtf(ev3);
  if (lo < 4) {
    float ev = (lo == 0) ? ev0 : (lo == 1) ? ev1 : (lo == 2) ? ev2 : ev3;
    evs[erow + lo] = ev;
  }
  // msg overwrite (own wave's rows; same-wave ordering)
#pragma unroll
  for (int i = 0; i < 4; ++i) {
    const float se = (i == 0) ? se0 : (i == 1) ? se1 : (i == 2) ? se2 : se3;
    float* xr = &xs[(erow + i) * 68 + lo];
#pragma unroll
    for (int t = 0; t < 4; ++t) {
      xr[16 * t] = se * xr[16 * t] * acv[t][i];
    }
  }
  __builtin_amdgcn_wave_barrier();
  // segmented reduce over this wave's 16 rows; lane = channel
  {
    const int c = lane;
    float acc = 0.f, evacc = 0.f;
    int prev = ed[0];
#pragma unroll
    for (int r = 0; r < 16; ++r) {
      int d = ed[r];
      if (d != prev) {
        unsafeAtomicAdd(&U[prev * 64 + c], acc);
        if (c == 0) unsafeAtomicAdd(&z[prev], evacc);
        acc = 0.f; evacc = 0.f; prev = d;
      }
      acc += xs[r * 68 + c];
      if (c == 0) evacc += evs[r];
    }
    unsafeAtomicAdd(&U[prev * 64 + c], acc);
    if (c == 0) unsafeAtomicAdd(&z[prev], evacc);
  }
}

// ---------- final (MFMA): out = s*(U@Wlv) + einsum(nf,na,Wsc) ----------
__global__ __launch_bounds__(256, 4) void final_kernel(
    const float* __restrict__ nf, const float* __restrict__ na,
    const float* __restrict__ U, const float* __restrict__ z,
    const unsigned short* __restrict__ wscb, const unsigned short* __restrict__ wlvb,
    float* __restrict__ out)
{
  __shared__ float nfl[64 * 68];
  __shared__ float Ul[64 * 68];
  __shared__ float nal[64 * 17];
  __shared__ float sl[64];
  const int tid = threadIdx.x;
  const int lane = tid & 63;
  const int lo = lane & 15, hi = lane >> 4;
  const int w = tid >> 6;
  const int nb = blockIdx.x * 64;

#pragma unroll
  for (int r = 0; r < 4; ++r) {
    int idx = tid + r * 256;
    int row = idx >> 4, c4 = idx & 15;
    int n = nb + row; if (n >= NN) n = NN - 1;
    float4 v = reinterpret_cast<const float4*>(nf)[n * 16 + c4];
    *reinterpret_cast<float4*>(&nfl[row * 68 + c4 * 4]) = v;
    float4 u = reinterpret_cast<const float4*>(U)[n * 16 + c4];
    *reinterpret_cast<float4*>(&Ul[row * 68 + c4 * 4]) = u;
  }
#pragma unroll
  for (int r = 0; r < 4; ++r) {
    int idx = tid + r * 256;
    int row = idx >> 4, p = idx & 15;
    int n = nb + row; if (n >= NN) n = NN - 1;
    nal[row * 17 + p] = na[n * 16 + p];
  }
  if (tid < 64) {
    int n = nb + tid; if (n >= NN) n = NN - 1;
    float zz = z[n];
    sl[tid] = (zz > 0.f) ? 0.5f * rsqrtf(zz) : 0.f;
  }
  __syncthreads();

  const int row = 16 * w + lo;
  short8v anf[2], au[2];
#pragma unroll
  for (int kk = 0; kk < 2; ++kk) {
#pragma unroll
    for (int j = 0; j < 8; ++j) {
      anf[kk][j] = bf16r(nfl[row * 68 + 32 * kk + 8 * hi + j]);
      au[kk][j]  = bf16r(Ul[row * 68 + 32 * kk + 8 * hi + j]);
    }
  }

  f32x4 zeroA = {0.f, 0.f, 0.f, 0.f};
  f32x4 accS[4] = {zeroA, zeroA, zeroA, zeroA};
  f32x4 accU[4] = {zeroA, zeroA, zeroA, zeroA};

#pragma unroll
  for (int t = 0; t < 4; ++t) {
    short8v b0 = *reinterpret_cast<const short8v*>(&wlvb[(16 * t + lo) * 64 + 8 * hi]);
    short8v b1 = *reinterpret_cast<const short8v*>(&wlvb[(16 * t + lo) * 64 + 32 + 8 * hi]);
    accU[t] = __builtin_amdgcn_mfma_f32_16x16x32_bf16(au[0], b0, accU[t], 0, 0, 0);
    accU[t] = __builtin_amdgcn_mfma_f32_16x16x32_bf16(au[1], b1, accU[t], 0, 0, 0);
  }
#pragma unroll 1
  for (int p = 0; p < 16; ++p) {
    f32x4 cp[4] = {zeroA, zeroA, zeroA, zeroA};
#pragma unroll
    for (int t = 0; t < 4; ++t) {
      const int bbase = (p * 64 + 16 * t + lo) * 64 + 8 * hi;
      short8v b0 = *reinterpret_cast<const short8v*>(&wscb[bbase]);
      short8v b1 = *reinterpret_cast<const short8v*>(&wscb[bbase + 32]);
      cp[t] = __builtin_amdgcn_mfma_f32_16x16x32_bf16(anf[0], b0, cp[t], 0, 0, 0);
      cp[t] = __builtin_amdgcn_mfma_f32_16x16x32_bf16(anf[1], b1, cp[t], 0, 0, 0);
    }
#pragma unroll
    for (int i = 0; i < 4; ++i) {
      float nav = nal[(16 * w + 4 * hi + i) * 17 + p];
#pragma unroll
      for (int t = 0; t < 4; ++t) accS[t][i] = fmaf(nav, cp[t][i], accS[t][i]);
    }
  }
#pragma unroll
  for (int i = 0; i < 4; ++i) {
    int n = nb + 16 * w + 4 * hi + i;
    if (n < NN) {
      float s = sl[16 * w + 4 * hi + i];
#pragma unroll
      for (int t = 0; t < 4; ++t) {
        out[n * 64 + 16 * t + lo] = fmaf(s, accU[t][i], accS[t][i]);
      }
    }
  }
}

extern "C" void kernel_launch(void* const* d_in, const int* in_sizes, int n_in,
                              void* d_out, int out_size, void* d_ws, size_t ws_size,
                              hipStream_t stream) {
  const float* nf   = (const float*)d_in[0];
  const float* na   = (const float*)d_in[1];
  const float* eb   = (const float*)d_in[2];
  const float* ea   = (const float*)d_in[3];
  const float* pos  = (const float*)d_in[4];
  const int*   esrc = (const int*)d_in[5];
  const int*   edst = (const int*)d_in[6];
  const float* Wq   = (const float*)d_in[7];
  const float* W1k  = (const float*)d_in[8];
  const float* W2k  = (const float*)d_in[9];
  const float* W1v  = (const float*)d_in[10];
  const float* W2v  = (const float*)d_in[11];
  const float* Wlk  = (const float*)d_in[12];
  const float* Wlv  = (const float*)d_in[13];
  const float* Wdot = (const float*)d_in[14];
  const float* Wsc  = (const float*)d_in[15];
  float* out = (float*)d_out;

  float* wsf = (float*)d_ws;
  float* z    = wsf;                        // 50,176
  float* U    = wsf + 50176;                // 3,200,000
  float* tq   = wsf + 3250176;              // 3,200,000
  unsigned short* w2kT = (unsigned short*)(wsf + 6450176);
  unsigned short* w2vT = (unsigned short*)(wsf + 6451200);
  unsigned short* wlvb = (unsigned short*)(wsf + 6452224);
  unsigned short* wscb = (unsigned short*)(wsf + 6454272);
  int*   cur  = (int*)(wsf + 6487040);
  int*   bsum = (int*)(wsf + 6537216);
  float* M    = wsf + 6537472;
  float* rec  = wsf + 6541568;              // 9,600,000 (48 B/edge, linear)
  int*   perm = (int*)(wsf + 16141568);     // 800,000

  prep_kernel<<<453, 256, 0, stream>>>(Wq, Wdot, Wlk, W2k, W2v, Wlv, Wsc,
                                       M, w2kT, w2vT, wlvb, wscb, cur);
  tq_kernel<<<(NN + 63) / 64, 256, 0, stream>>>(nf, M, tq);
  hist_zero<<<EE / 256, 256, 0, stream>>>(edst, cur, (float4*)z);
  scanA_kernel<<<NPAD / 256, 256, 0, stream>>>(cur, bsum);
  scanB_kernel<<<1, 256, 0, stream>>>(bsum);
  scatter_fused<<<EE / 256, 256, 0, stream>>>(esrc, edst, ea, eb, pos, W1k, W1v,
                                              cur, bsum, perm, rec);
  edge_kernel<<<EE / 64, 256, 0, stream>>>(nf, tq, rec, perm, esrc, edst,
                                           w2kT, w2vT, z, U);
  final_kernel<<<(NN + 63) / 64, 256, 0, stream>>>(nf, na, U, z, wscb, wlvb, out);
}